// Round 9
// baseline (729.659 us; speedup 1.0000x reference)
//
#include <hip/hip_runtime.h>
#include <math.h>

typedef unsigned short ushort_t;
typedef __attribute__((ext_vector_type(8))) short short8;
typedef __attribute__((ext_vector_type(4))) float f32x4;

#define B_   8
#define L_   1024
#define NS_  512
#define D_   512
#define NH_  8
#define HE_  2048
#define EPS_ 1e-5f

#define MFMA16(a, b, c) __builtin_amdgcn_mfma_f32_16x16x32_bf16(a, b, c, 0, 0, 0)
#define GL2LDS(g, l) __builtin_amdgcn_global_load_lds( \
    (const __attribute__((address_space(1))) unsigned int*)(g), \
    (__attribute__((address_space(3))) unsigned int*)(l), 16, 0, 0)

__device__ __forceinline__ ushort_t f2bf(float f) {
  unsigned u = __float_as_uint(f);
  unsigned r = (u + 0x7fffu + ((u >> 16) & 1u)) >> 16;
  return (ushort_t)r;
}

// ---------------------------------------------------------------------------
// Stage a 128x32 bf16 tile (8 KB) with 2-bit XOR-swizzle (BK=32 variant):
// LDS dest linear; SOURCE chunk sc = (c&3) ^ ((row^(row>>2))&3).  Readers use
// chunk quad ^ ((r^(r>>2))&3) -> 2-way max bank aliasing (free, m136).
// ---------------------------------------------------------------------------
__device__ __forceinline__ void stage_tile32s(const ushort_t* __restrict__ g0,
                                              int ld, ushort_t* lds) {
  const int t = threadIdx.x;
  const int w = t >> 6, lane = t & 63;
#pragma unroll
  for (int j = 0; j < 2; ++j) {
    const int c = w * 64 + j * 256 + lane;
    const int row = c >> 2;
    const int sc = (c & 3) ^ ((row ^ (row >> 2)) & 3);
    GL2LDS(g0 + (size_t)row * ld + sc * 8, lds + (size_t)(w * 64 + j * 256) * 8);
  }
}

// ---------------------------------------------------------------------------
// Stage a 128x64 bf16 tile (16 KB) with XOR-swizzle (T2, rule #21):
// LDS dest stays linear; SOURCE chunk is inverse-swizzled so LDS chunk c
// holds global chunk (c&7)^(row&7).  Readers XOR chunk idx with (row&7).
// ---------------------------------------------------------------------------
__device__ __forceinline__ void stage_tile64(const ushort_t* __restrict__ g0,
                                             int ld, ushort_t* lds) {
  const int t = threadIdx.x;
  const int w = t >> 6, lane = t & 63;
#pragma unroll
  for (int j = 0; j < 4; ++j) {
    const int c = w * 64 + j * 256 + lane;
    const int row = c >> 3;
    const int sc = (c & 7) ^ (row & 7);
    GL2LDS(g0 + (size_t)row * ld + sc * 8, lds + (size_t)(w * 64 + j * 256) * 8);
  }
}

// ---------------------------------------------------------------------------
// Kernel 1a: noise embedding MLP + router top-2.  grid (B), 1024 thr.
// ---------------------------------------------------------------------------
__global__ __launch_bounds__(1024) void noise_embed(
    const float* __restrict__ t_in,
    const float* __restrict__ w1, const float* __restrict__ b1,
    const float* __restrict__ w2, const float* __restrict__ b2,
    const float* __restrict__ rw,
    float* __restrict__ nc_out,
    float* __restrict__ tw_out, int* __restrict__ ti_out)
{
  const int b = blockIdx.x;
  const int t = threadIdx.x;
  __shared__ float temb[512];
  __shared__ float h1[256];
  __shared__ float ncs[256];
  __shared__ float lg[8];
  const float tv = t_in[b];
  if (t < 512) {
    const int k = t & 255;
    float fr = __expf(-logf(10000.0f) * (float)k / 255.0f);
    float ang = tv * fr;
    temb[t] = (t < 256) ? cosf(ang) : sinf(ang);
  }
  __syncthreads();
  const int col = t >> 2, part = t & 3;
  {
    float s = 0.f;
    const float* wp = w1 + (size_t)(part * 128) * 256 + col;
    const float* tp = temb + part * 128;
#pragma unroll 32
    for (int i = 0; i < 128; ++i) s += tp[i] * wp[(size_t)i * 256];
    s += __shfl_xor(s, 1, 64);
    s += __shfl_xor(s, 2, 64);
    if (part == 0) {
      s += b1[col];
      h1[col] = s / (1.0f + __expf(-s));
    }
  }
  __syncthreads();
  {
    float s = 0.f;
    const float* wp = w2 + (size_t)(part * 64) * 256 + col;
    const float* hp = h1 + part * 64;
#pragma unroll 32
    for (int i = 0; i < 64; ++i) s += hp[i] * wp[(size_t)i * 256];
    s += __shfl_xor(s, 1, 64);
    s += __shfl_xor(s, 2, 64);
    if (part == 0) {
      s += b2[col];
      ncs[col] = s;
      nc_out[b * 256 + col] = s;
    }
  }
  __syncthreads();
  if (t < 64) {
    const int e = t >> 3, seg = t & 7;
    float s = 0.f;
#pragma unroll
    for (int i = 0; i < 32; ++i) s += ncs[seg * 32 + i] * rw[(seg * 32 + i) * 8 + e];
    s += __shfl_xor(s, 1, 64);
    s += __shfl_xor(s, 2, 64);
    s += __shfl_xor(s, 4, 64);
    if (seg == 0) lg[e] = s;
  }
  __syncthreads();
  if (t == 0) {
    float mx = lg[0];
    for (int e = 1; e < 8; ++e) mx = fmaxf(mx, lg[e]);
    float z = 0.f, p[8];
    for (int e = 0; e < 8; ++e) { p[e] = __expf(lg[e] - mx); z += p[e]; }
    for (int e = 0; e < 8; ++e) p[e] /= z;
    int i0 = 0;
    for (int e = 1; e < 8; ++e) if (p[e] > p[i0]) i0 = e;
    int i1 = (i0 == 0) ? 1 : 0;
    for (int e = 0; e < 8; ++e) if (e != i0 && p[e] > p[i1]) i1 = e;
    float s01 = fmaxf(p[i0] + p[i1], 1e-8f);
    tw_out[b * 2 + 0] = p[i0] / s01;
    tw_out[b * 2 + 1] = p[i1] / s01;
    ti_out[b * 2 + 0] = i0;
    ti_out[b * 2 + 1] = i1;
  }
}

// ---------------------------------------------------------------------------
// Kernel 1b: AdaLN modulation projections.  grid (B, 8), 1024 thr.
// ---------------------------------------------------------------------------
__global__ __launch_bounds__(1024) void mod_proj(
    const float* __restrict__ nc,
    const float* __restrict__ ncsa_w, const float* __restrict__ ncsa_b,
    const float* __restrict__ moe_w, const float* __restrict__ moe_b,
    float* __restrict__ ncsa_mod, float* __restrict__ moe_mod)
{
  const int b = blockIdx.x, cg = blockIdx.y;
  const int t = threadIdx.x;
  __shared__ float ncs[256];
  if (t < 256) ncs[t] = nc[b * 256 + t];
  __syncthreads();
  const int idx = t >> 2, part = t & 3;
  const int half = idx >> 7;
  const int col = cg * 128 + (idx & 127);
  const float* wsel = half ? moe_w : ncsa_w;
  float s = 0.f;
  const float* wp = wsel + (size_t)(part * 64) * 1024 + col;
  const float* np = ncs + part * 64;
#pragma unroll 32
  for (int i = 0; i < 64; ++i) s += np[i] * wp[(size_t)i * 1024];
  s += __shfl_xor(s, 1, 64);
  s += __shfl_xor(s, 2, 64);
  if (part == 0) {
    const float* bsel = half ? moe_b : ncsa_b;
    float* osel = half ? moe_mod : ncsa_mod;
    osel[b * 1024 + col] = s + bsel[col];
  }
}

// ---------------------------------------------------------------------------
// Kernel 2: LayerNorm + modulation -> bf16 output.
// ---------------------------------------------------------------------------
__global__ __launch_bounds__(256) void ln_mod_kernel(
    const float* __restrict__ X, const float* __restrict__ gvec,
    const float* __restrict__ bvec, const float* __restrict__ mod,
    ushort_t* __restrict__ Y)
{
  const int row = blockIdx.x;
  const int b = row >> 10;
  const int t = threadIdx.x;
  const float* xr = X + (size_t)row * 512;
  float2 v = *(const float2*)(xr + t * 2);
  float s = v.x + v.y;
  float q = v.x * v.x + v.y * v.y;
#pragma unroll
  for (int off = 32; off > 0; off >>= 1) {
    s += __shfl_down(s, off, 64);
    q += __shfl_down(q, off, 64);
  }
  __shared__ float ws_[4], wq_[4], smu[1], sinv[1];
  if ((t & 63) == 0) { ws_[t >> 6] = s; wq_[t >> 6] = q; }
  __syncthreads();
  if (t == 0) {
    float S = ws_[0] + ws_[1] + ws_[2] + ws_[3];
    float Q = wq_[0] + wq_[1] + wq_[2] + wq_[3];
    float mu = S * (1.0f / 512.0f);
    float var = Q * (1.0f / 512.0f) - mu * mu;
    smu[0] = mu;
    sinv[0] = rsqrtf(var + EPS_);
  }
  __syncthreads();
  const float mu = smu[0], inv = sinv[0];
  const int d0 = t * 2;
  float scx, scy, shx, shy;
  if (mod) {
    const float* mrow = mod + (size_t)b * 1024;
    scx = 1.0f + mrow[512 + d0]; scy = 1.0f + mrow[512 + d0 + 1];
    shx = mrow[d0];              shy = mrow[d0 + 1];
  } else {
    scx = gvec[d0]; scy = gvec[d0 + 1];
    shx = bvec[d0]; shy = bvec[d0 + 1];
  }
  float ox = (v.x - mu) * inv * scx + shx;
  float oy = (v.y - mu) * inv * scy + shy;
  unsigned pk = (unsigned)f2bf(ox) | ((unsigned)f2bf(oy) << 16);
  *(unsigned*)(Y + (size_t)row * 512 + d0) = pk;
}

// ---------------------------------------------------------------------------
// Kernel 3a: tiled transpose + fp32->bf16:  in[z][R][C] -> out[z][C][R]
// ---------------------------------------------------------------------------
__global__ __launch_bounds__(256) void transpose_cvt(
    const float* __restrict__ in, ushort_t* __restrict__ out,
    int R, int C, long ibs, long obs)
{
  __shared__ float tile[32][33];
  const float* src = in + (size_t)blockIdx.z * ibs;
  ushort_t* dst = out + (size_t)blockIdx.z * obs;
  const int c0 = blockIdx.x * 32, r0 = blockIdx.y * 32;
  const int tx = threadIdx.x & 31, ty = threadIdx.x >> 5;
  for (int rr = ty; rr < 32; rr += 8)
    tile[rr][tx] = src[(size_t)(r0 + rr) * C + c0 + tx];
  __syncthreads();
  for (int rr = ty; rr < 32; rr += 8)
    dst[(size_t)(c0 + rr) * R + r0 + tx] = f2bf(tile[tx][rr]);
}

// Kernel 3a'': interleaved transpose for fc_in_w: in[e][512][4096] ->
// out[e][4096][512] where out row c holds source col (c>>1) + (c&1)*2048.
// Permutation applied on the WRITE side: block reads a contiguous 32x32
// source tile (full 128B-coalesced reads); source col sc maps to dst row
// ((sc&2047)<<1) | (sc>>11).
__global__ __launch_bounds__(256) void transpose_cvt_ileave(
    const float* __restrict__ in, ushort_t* __restrict__ out)
{
  __shared__ float tile[32][33];
  const int e = blockIdx.z;
  const int sc0 = blockIdx.x * 32, d0 = blockIdx.y * 32;
  const int tx = threadIdx.x & 31, ty = threadIdx.x >> 5;
  const float* src = in + (size_t)e * 512 * 4096;
  ushort_t* dst = out + (size_t)e * 4096 * 512;
  const int half = sc0 >> 11;        // whole block is one half (32 | 2048)
  for (int rr = ty; rr < 32; rr += 8)
    tile[rr][tx] = src[(size_t)(d0 + rr) * 4096 + sc0 + tx];
  __syncthreads();
  for (int rr = ty; rr < 32; rr += 8) {
    const int drow = (((sc0 + rr) & 2047) << 1) | half;
    dst[(size_t)drow * 512 + d0 + tx] = f2bf(tile[tx][rr]);
  }
}

// Kernel 3a': 8 dense 512x512 transposes in one dispatch (z selects source).
struct P8 { const float* p[8]; };
__global__ __launch_bounds__(256) void transpose_cvt8(
    P8 srcs, ushort_t* __restrict__ out)
{
  __shared__ float tile[32][33];
  const float* src = srcs.p[blockIdx.z];
  ushort_t* dst = out + (size_t)blockIdx.z * 512 * 512;
  const int c0 = blockIdx.x * 32, r0 = blockIdx.y * 32;
  const int tx = threadIdx.x & 31, ty = threadIdx.x >> 5;
  for (int rr = ty; rr < 32; rr += 8)
    tile[rr][tx] = src[(size_t)(r0 + rr) * 512 + c0 + tx];
  __syncthreads();
  for (int rr = ty; rr < 32; rr += 8)
    dst[(size_t)(c0 + rr) * 512 + r0 + tx] = f2bf(tile[tx][rr]);
}

// Kernel 3b: plain fp32->bf16 cast (4 elems/thread)
__global__ __launch_bounds__(256) void cvt_bf16(
    const float* __restrict__ in, ushort_t* __restrict__ out)
{
  const int i = (blockIdx.x * 256 + threadIdx.x) * 4;
  float4 v = *(const float4*)(in + i);
  uint2 pk;
  pk.x = (unsigned)f2bf(v.x) | ((unsigned)f2bf(v.y) << 16);
  pk.y = (unsigned)f2bf(v.z) | ((unsigned)f2bf(v.w) << 16);
  *(uint2*)(out + i) = pk;
}

// ---------------------------------------------------------------------------
// Kernel 4: bf16 MFMA GEMM.  C[M,N] = A[M,K](bf16) @ Bt[N,K]^T + bias (+resid)
// 128x128 tile, BK=64 swizzled LDS (T2), 4 waves, double-buffered (64 KB).
// ---------------------------------------------------------------------------
struct B3 { const float* p[3]; };
__global__ __launch_bounds__(256) void gemm_bf16(
    const ushort_t* __restrict__ A, const ushort_t* __restrict__ Bt,
    B3 bias, const float* __restrict__ resid,
    void* __restrict__ Cout, int M, int N, int K, int bf16_out)
{
  __shared__ ushort_t As[2][8192];
  __shared__ ushort_t Bs[2][8192];
  const int t = threadIdx.x;
  const int w = t >> 6, lane = t & 63;
  const int quad = lane >> 4, r = lane & 15;
  const int sw = r & 7;
  const int wm = w >> 1, wn = w & 1;
  const int gx = gridDim.x;
  const int T = gx * gridDim.y;
  const int lid = blockIdx.x + gx * blockIdx.y;
  const int nl = (lid & 7) * (T >> 3) + (lid >> 3);
  const int bm = (nl / gx) * 128, bn = (nl % gx) * 128;
  f32x4 acc[4][4];
#pragma unroll
  for (int i = 0; i < 4; ++i)
#pragma unroll
    for (int j = 0; j < 4; ++j) acc[i][j] = (f32x4){0.f, 0.f, 0.f, 0.f};
  const ushort_t* Ab = A + (size_t)bm * K;
  const ushort_t* Bb = Bt + (size_t)bn * K;
  const int NIT = K >> 6;
  stage_tile64(Ab, K, As[0]);
  stage_tile64(Bb, K, Bs[0]);
  __syncthreads();
  for (int it = 0; it < NIT; ++it) {
    const int cur = it & 1;
    if (it + 1 < NIT) {
      stage_tile64(Ab + (it + 1) * 64, K, As[cur ^ 1]);
      stage_tile64(Bb + (it + 1) * 64, K, Bs[cur ^ 1]);
    }
#pragma unroll
    for (int ki = 0; ki < 2; ++ki) {
      const int ch = (((ki << 2) | quad) ^ sw) * 8;
      short8 af[4], bfg[4];
#pragma unroll
      for (int i = 0; i < 4; ++i)
        af[i] = *(const short8*)&As[cur][(wm * 64 + i * 16 + r) * 64 + ch];
#pragma unroll
      for (int j = 0; j < 4; ++j)
        bfg[j] = *(const short8*)&Bs[cur][(wn * 64 + j * 16 + r) * 64 + ch];
#pragma unroll
      for (int i = 0; i < 4; ++i)
#pragma unroll
        for (int j = 0; j < 4; ++j)
          acc[i][j] = MFMA16(af[i], bfg[j], acc[i][j]);
    }
    __syncthreads();
  }
  if (bf16_out) {
    ushort_t* Cb = (ushort_t*)Cout;
#pragma unroll
    for (int j = 0; j < 4; ++j) {
      const int col = bn + wn * 64 + j * 16 + r;
      const float bia = bias.p[col >> 9][col & 511];
#pragma unroll
      for (int i = 0; i < 4; ++i)
#pragma unroll
        for (int reg = 0; reg < 4; ++reg) {
          const int row = bm + wm * 64 + i * 16 + quad * 4 + reg;
          Cb[(size_t)row * N + col] = f2bf(acc[i][j][reg] + bia);
        }
    }
  } else {
    float* Cf = (float*)Cout;
#pragma unroll
    for (int j = 0; j < 4; ++j) {
      const int col = bn + wn * 64 + j * 16 + r;
      const float bia = bias.p[col >> 9][col & 511];
#pragma unroll
      for (int i = 0; i < 4; ++i)
#pragma unroll
        for (int reg = 0; reg < 4; ++reg) {
          const int row = bm + wm * 64 + i * 16 + quad * 4 + reg;
          float v = acc[i][j][reg] + bia;
          if (resid) v += resid[(size_t)row * N + col];
          Cf[(size_t)row * N + col] = v;
        }
    }
  }
}

// ---------------------------------------------------------------------------
// Kernel 5: MFMA flash attention, bf16 Q/K/V in, bf16 out.
// Flat grid of 512 blocks x 512 thr (8 waves); each block = 128 queries,
// wave w owns queries w*16..w*16+15.  XCD grouping: bid&7 -> XCD.
// ---------------------------------------------------------------------------
__global__ __launch_bounds__(512, 4) void fattn_mfma(
    const ushort_t* __restrict__ Q, const ushort_t* __restrict__ Kmat,
    const ushort_t* __restrict__ V, ushort_t* __restrict__ O, int Lk,
    int ldq, int ldkv)
{
  __shared__ __align__(16) ushort_t Ks[64][72];      // [key][d]
  __shared__ __align__(16) ushort_t Vt[64][72];      // [d][key]
  __shared__ __align__(16) ushort_t Pt[8][16][72];   // per-wave [q_local][key]
  const int t = threadIdx.x;
  const int w = t >> 6, lane = t & 63;
  const int quad = lane >> 4, r = lane & 15;
  const int bid = blockIdx.x;
  const int xcd = bid & 7, jj = bid >> 3;
  const int qi = jj & 7;                 // q-tile 0..7
  const int g = xcd + 8 * (jj >> 3);     // (b,h) group 0..63
  const int h = g & 7, b = g >> 3;
  const int q0 = qi * 128;
  const size_t hoff = (size_t)h * 64;
  const ushort_t* Qb = Q + ((size_t)b * 1024 + q0) * ldq + hoff;
  const ushort_t* Kb = Kmat + (size_t)b * Lk * ldkv + hoff;
  const ushort_t* Vb = V + (size_t)b * Lk * ldkv + hoff;

  short8 qb[2];
#pragma unroll
  for (int ki = 0; ki < 2; ++ki)
    qb[ki] = *(const short8*)(Qb + (size_t)(w * 16 + r) * ldq +
                              ki * 32 + quad * 8);

  f32x4 oacc[4];
#pragma unroll
  for (int rt = 0; rt < 4; ++rt) oacc[rt] = (f32x4){0.f, 0.f, 0.f, 0.f};
  float m_ = -1e30f;
  float l_ = 0.f;

  uint4 kr, vr, kn, vn;
  const int dof = w * 8;                 // this wave's d-slice of K/V rows
  auto ldkvf = [&](int k0, uint4& kp, uint4& vp) {
    kp = *(const uint4*)(Kb + (size_t)(k0 + lane) * ldkv + dof);
    vp = *(const uint4*)(Vb + (size_t)(k0 + lane) * ldkv + dof);
  };
  auto stkv = [&](const uint4& kp, const uint4& vp) {
    *(uint4*)&Ks[lane][dof] = kp;
    const ushort_t* vv = (const ushort_t*)&vp;
#pragma unroll
    for (int i = 0; i < 8; ++i) Vt[dof + i][lane] = vv[i];  // transpose
  };

  ldkvf(0, kr, vr);
  const int nch = Lk >> 6;
  for (int c = 0; c < nch; ++c) {
    stkv(kr, vr);
    __syncthreads();
    if (c + 1 < nch) ldkvf((c + 1) << 6, kn, vn);

    // ---- S^T = K · Q^T ----
    f32x4 sacc[4];
#pragma unroll
    for (int rt = 0; rt < 4; ++rt) sacc[rt] = (f32x4){0.f, 0.f, 0.f, 0.f};
    __builtin_amdgcn_s_setprio(1);
#pragma unroll
    for (int ki = 0; ki < 2; ++ki) {
      short8 kf[4];
#pragma unroll
      for (int rt = 0; rt < 4; ++rt)
        kf[rt] = *(const short8*)&Ks[rt * 16 + r][ki * 32 + quad * 8];
#pragma unroll
      for (int rt = 0; rt < 4; ++rt)
        sacc[rt] = MFMA16(kf[rt], qb[ki], sacc[rt]);
    }
    __builtin_amdgcn_s_setprio(0);

    // ---- online softmax with defer-max (T13) ----
    {
      float vmax = sacc[0][0];
#pragma unroll
      for (int rt = 0; rt < 4; ++rt)
#pragma unroll
        for (int reg = 0; reg < 4; ++reg) vmax = fmaxf(vmax, sacc[rt][reg]);
      vmax = fmaxf(vmax, __shfl_xor(vmax, 16, 64));
      vmax = fmaxf(vmax, __shfl_xor(vmax, 32, 64));
      const float pm = vmax * 0.125f;
      if (__any(pm > m_ + 8.f)) {
        const float mnew = fmaxf(m_, pm);
        const float corr = __expf(m_ - mnew);
        m_ = mnew;
        l_ *= corr;
#pragma unroll
        for (int rt = 0; rt < 4; ++rt)
#pragma unroll
          for (int reg = 0; reg < 4; ++reg) oacc[rt][reg] *= corr;
      }
      const float mcur = m_;
      float ps = 0.f;
#pragma unroll
      for (int rt = 0; rt < 4; ++rt) {
        float p0 = __expf(fmaf(sacc[rt][0], 0.125f, -mcur));
        float p1 = __expf(fmaf(sacc[rt][1], 0.125f, -mcur));
        float p2 = __expf(fmaf(sacc[rt][2], 0.125f, -mcur));
        float p3 = __expf(fmaf(sacc[rt][3], 0.125f, -mcur));
        ps += (p0 + p1) + (p2 + p3);
        uint2 pk;
        pk.x = (unsigned)f2bf(p0) | ((unsigned)f2bf(p1) << 16);
        pk.y = (unsigned)f2bf(p2) | ((unsigned)f2bf(p3) << 16);
        *(uint2*)&Pt[w][r][rt * 16 + quad * 4] = pk;
      }
      ps += __shfl_xor(ps, 16, 64);
      ps += __shfl_xor(ps, 32, 64);
      l_ += ps;
    }

    // ---- O^T += V^T · P^T ----
    __builtin_amdgcn_s_setprio(1);
#pragma unroll
    for (int ki = 0; ki < 2; ++ki) {
      short8 vf[4], pf;
#pragma unroll
      for (int rt = 0; rt < 4; ++rt)
        vf[rt] = *(const short8*)&Vt[rt * 16 + r][ki * 32 + quad * 8];
      pf = *(const short8*)&Pt[w][r][ki * 32 + quad * 8];
#pragma unroll
      for (int rt = 0; rt < 4; ++rt)
        oacc[rt] = MFMA16(vf[rt], pf, oacc[rt]);
    }
    __builtin_amdgcn_s_setprio(0);
    __syncthreads();
    kr = kn; vr = vn;
  }

  // ---- epilogue ----
  {
    const float inv = 1.0f / l_;
    const int qg = q0 + w * 16 + r;
    ushort_t* op = O + ((size_t)b * 1024 + qg) * 512 + hoff;
#pragma unroll
    for (int rt = 0; rt < 4; ++rt) {
      uint2 pk;
      pk.x = (unsigned)f2bf(oacc[rt][0] * inv) |
             ((unsigned)f2bf(oacc[rt][1] * inv) << 16);
      pk.y = (unsigned)f2bf(oacc[rt][2] * inv) |
             ((unsigned)f2bf(oacc[rt][3] * inv) << 16);
      *(uint2*)(op + rt * 16 + quad * 4) = pk;
    }
  }
}

// ---------------------------------------------------------------------------
// Kernel 6: MoE fc_in for ONE slot, interleaved-weight GEMM.  flat 2048 blks.
// WiT_int[e][4096][512]: row c = source col (c>>1)+(c&1)*2048; SwiGLU fuses
// via shfl_xor(.,1).  BK=32 + 2-bit swizzle, 32 KB LDS -> 5 blocks/CU
// (round-8: 64 KB capped at 2 blocks/CU, Occupancy 19%, barrier-drain bound).
// XCD remap: b == xcd; r0 inner (8 consecutive blocks share a weight panel).
// ---------------------------------------------------------------------------
__global__ __launch_bounds__(256, 5) void moe_fcin(
    const ushort_t* __restrict__ Xm, const ushort_t* __restrict__ WiT,
    const float* __restrict__ Bi, const float* __restrict__ tw,
    const int* __restrict__ ti, ushort_t* __restrict__ Hid, int ks)
{
  __shared__ ushort_t As[2][4096];
  __shared__ ushort_t Bs[2][4096];
  const int t = threadIdx.x;
  const int w = t >> 6, lane = t & 63;
  const int quad = lane >> 4, r = lane & 15;
  const int sw = (r ^ (r >> 2)) & 3;
  const int wm = w >> 1, wn = w & 1;
  const int lid = blockIdx.x;
  const int nl = (lid & 7) * 256 + (lid >> 3);
  const int r0 = (nl & 7) * 128;           // inner: A row-band
  const int n0 = ((nl >> 3) & 31) * 128;   // middle: weight panel
  const int b = nl >> 8;
  const int e = ti[b * 2 + ks];
  const float wq = tw[b * 2 + ks];
  f32x4 acc[4][4];
#pragma unroll
  for (int i = 0; i < 4; ++i)
#pragma unroll
    for (int j = 0; j < 4; ++j) acc[i][j] = (f32x4){0.f, 0.f, 0.f, 0.f};
  const ushort_t* Ab = Xm + ((size_t)b * 1024 + r0) * 512;
  const ushort_t* Bb = WiT + (size_t)e * 4096 * 512 + (size_t)n0 * 512;
  stage_tile32s(Ab, 512, As[0]);
  stage_tile32s(Bb, 512, Bs[0]);
  __syncthreads();
  for (int it = 0; it < 16; ++it) {
    const int cur = it & 1;
    if (it + 1 < 16) {
      stage_tile32s(Ab + (it + 1) * 32, 512, As[cur ^ 1]);
      stage_tile32s(Bb + (it + 1) * 32, 512, Bs[cur ^ 1]);
    }
    const int ch = (quad ^ sw) * 8;
    short8 af[4], bfg[4];
#pragma unroll
    for (int i = 0; i < 4; ++i)
      af[i] = *(const short8*)&As[cur][(wm * 64 + i * 16 + r) * 32 + ch];
#pragma unroll
    for (int j = 0; j < 4; ++j)
      bfg[j] = *(const short8*)&Bs[cur][(wn * 64 + j * 16 + r) * 32 + ch];
#pragma unroll
    for (int i = 0; i < 4; ++i)
#pragma unroll
      for (int j = 0; j < 4; ++j)
        acc[i][j] = MFMA16(af[i], bfg[j], acc[i][j]);
    __syncthreads();
  }
  // epilogue: col = interleaved index; oc = col>>1; even lane = val, odd = gate
  ushort_t* Hb = Hid + (size_t)b * 1024 * 2048;
#pragma unroll
  for (int j = 0; j < 4; ++j) {
    const int col = n0 + wn * 64 + j * 16 + r;
    const int oc = col >> 1;
    const float bia = Bi[(size_t)e * 4096 + oc + (col & 1) * 2048];
#pragma unroll
    for (int i = 0; i < 4; ++i)
#pragma unroll
      for (int reg = 0; reg < 4; ++reg) {
        const float mine = acc[i][j][reg] + bia;
        const float part = __shfl_xor(mine, 1, 64);
        if ((r & 1) == 0) {
          const float gg = part;                       // odd lane held gate
          const float hv = mine * (gg / (1.0f + __expf(-gg))) * wq;
          const int lrow = r0 + wm * 64 + i * 16 + quad * 4 + reg;
          Hb[(size_t)lrow * 2048 + oc] = f2bf(hv);
        }
      }
  }
}

// ---------------------------------------------------------------------------
// Kernel 7: MoE fc_out for ONE slot.  flat grid 256, 256 thr.  BK=64 + T2.
// first=1: Out = X2 + acc + (tw0*bo_e0 + tw1*bo_e1);  first=0: Out += acc
// ---------------------------------------------------------------------------
__global__ __launch_bounds__(256) void moe_fcout(
    const ushort_t* __restrict__ Hid, const ushort_t* __restrict__ WoT,
    const float* __restrict__ Bo, const float* __restrict__ X2,
    const float* __restrict__ tw, const int* __restrict__ ti,
    float* __restrict__ Out, int ks, int first)
{
  __shared__ ushort_t As[2][8192];
  __shared__ ushort_t Bs[2][8192];
  const int t = threadIdx.x;
  const int w = t >> 6, lane = t & 63;
  const int quad = lane >> 4, r = lane & 15;
  const int sw = r & 7;
  const int wm = w >> 1, wn = w & 1;
  const int lid = blockIdx.x;
  const int nl = (lid & 7) * 32 + (lid >> 3);
  const int n0 = (nl & 3) * 128;
  const int r0 = ((nl >> 2) & 7) * 128;
  const int b = nl >> 5;
  const int e = ti[b * 2 + ks];
  f32x4 acc[4][4];
#pragma unroll
  for (int i = 0; i < 4; ++i)
#pragma unroll
    for (int j = 0; j < 4; ++j) acc[i][j] = (f32x4){0.f, 0.f, 0.f, 0.f};
  const ushort_t* Ab = Hid + ((size_t)b * 1024 + r0) * 2048;
  const ushort_t* Bb = WoT + (size_t)e * 512 * 2048 + (size_t)n0 * 2048;
  stage_tile64(Ab, 2048, As[0]);
  stage_tile64(Bb, 2048, Bs[0]);
  __syncthreads();
  for (int it = 0; it < 32; ++it) {
    const int cur = it & 1;
    if (it + 1 < 32) {
      stage_tile64(Ab + (it + 1) * 64, 2048, As[cur ^ 1]);
      stage_tile64(Bb + (it + 1) * 64, 2048, Bs[cur ^ 1]);
    }
#pragma unroll
    for (int ki = 0; ki < 2; ++ki) {
      const int ch = (((ki << 2) | quad) ^ sw) * 8;
      short8 af[4], bfg[4];
#pragma unroll
      for (int i = 0; i < 4; ++i)
        af[i] = *(const short8*)&As[cur][(wm * 64 + i * 16 + r) * 64 + ch];
#pragma unroll
      for (int j = 0; j < 4; ++j)
        bfg[j] = *(const short8*)&Bs[cur][(wn * 64 + j * 16 + r) * 64 + ch];
#pragma unroll
      for (int i = 0; i < 4; ++i)
#pragma unroll
        for (int j = 0; j < 4; ++j)
          acc[i][j] = MFMA16(af[i], bfg[j], acc[i][j]);
    }
    __syncthreads();
  }
  const int e0 = ti[b * 2], e1 = ti[b * 2 + 1];
  const float tw0 = tw[b * 2], tw1 = tw[b * 2 + 1];
#pragma unroll
  for (int j = 0; j < 4; ++j) {
    const int col = n0 + wn * 64 + j * 16 + r;
    const float badd = first ? (tw0 * Bo[(size_t)e0 * 512 + col] +
                                tw1 * Bo[(size_t)e1 * 512 + col]) : 0.f;
#pragma unroll
    for (int i = 0; i < 4; ++i)
#pragma unroll
      for (int reg = 0; reg < 4; ++reg) {
        const size_t row = (size_t)b * 1024 + r0 + wm * 64 + i * 16 + quad * 4 + reg;
        const size_t idx = row * 512 + col;
        const float base = first ? X2[idx] : Out[idx];
        Out[idx] = base + acc[i][j][reg] + badd;
      }
  }
}

// ---------------------------------------------------------------------------
// Launch.  Workspace: 93 MiB total.
// ---------------------------------------------------------------------------
extern "C" void kernel_launch(void* const* d_in, const int* in_sizes, int n_in,
                              void* d_out, int out_size, void* d_ws, size_t ws_size,
                              hipStream_t stream) {
  const float* x        = (const float*)d_in[0];
  const float* scene    = (const float*)d_in[1];
  const float* t_in     = (const float*)d_in[2];
  const float* sn_g     = (const float*)d_in[3];
  const float* sn_b     = (const float*)d_in[4];
  const float* ca_wq    = (const float*)d_in[5];
  const float* ca_bq    = (const float*)d_in[6];
  const float* ca_wk    = (const float*)d_in[7];
  const float* ca_bk    = (const float*)d_in[8];
  const float* ca_wv    = (const float*)d_in[9];
  const float* ca_bv    = (const float*)d_in[10];
  const float* ca_wo    = (const float*)d_in[11];
  const float* ca_bo    = (const float*)d_in[12];
  const float* sa_wq    = (const float*)d_in[13];
  const float* sa_bq    = (const float*)d_in[14];
  const float* sa_wk    = (const float*)d_in[15];
  const float* sa_bk    = (const float*)d_in[16];
  const float* sa_wv    = (const float*)d_in[17];
  const float* sa_bv    = (const float*)d_in[18];
  const float* sa_wo    = (const float*)d_in[19];
  const float* sa_bo    = (const float*)d_in[20];
  const float* ne_w1    = (const float*)d_in[21];
  const float* ne_b1    = (const float*)d_in[22];
  const float* ne_w2    = (const float*)d_in[23];
  const float* ne_b2    = (const float*)d_in[24];
  const float* ncsa_w   = (const float*)d_in[25];
  const float* ncsa_b   = (const float*)d_in[26];
  const float* moe_w    = (const float*)d_in[27];
  const float* moe_b    = (const float*)d_in[28];
  const float* router_w = (const float*)d_in[29];
  const float* fc_in_w  = (const float*)d_in[30];
  const float* fc_in_b  = (const float*)d_in[31];
  const float* fc_out_w = (const float*)d_in[32];
  const float* fc_out_b = (const float*)d_in[33];
  float* out = (float*)d_out;

  // ---- workspace layout (MiB offsets; 93 MiB total) ----
  char* W = (char*)d_ws;
  const size_t MB = 1u << 20;
  float* ncsa_mod = (float*)W;
  float* moe_mod  = ncsa_mod + 8192;
  float* tw       = moe_mod + 8192;
  int*   ti       = (int*)(tw + 16);
  float* nc_ws    = (float*)(ti + 16);            // [8][256]
  ushort_t* wT      = (ushort_t*)(W + 1 * MB);
  ushort_t* fciT    = (ushort_t*)(W + 5 * MB);
  ushort_t* fcoT    = (ushort_t*)(W + 37 * MB);
  ushort_t* xin_bf  = (ushort_t*)(W + 53 * MB);
  ushort_t* attn_bf = xin_bf;
  ushort_t* scene_bf= (ushort_t*)(W + 61 * MB);
  ushort_t* cq  = (ushort_t*)(W + 65 * MB);
  ushort_t* ckv = (ushort_t*)(W + 73 * MB);
  ushort_t* qkv = (ushort_t*)(W + 65 * MB);
  ushort_t* hid = (ushort_t*)(W + 61 * MB);
  float* x1 = out;

  const int WSZ = 512 * 512;

  // noise path: embed+router (8 blocks x 1024 thr), then mods (64 x 1024 thr)
  noise_embed<<<dim3(B_), dim3(1024), 0, stream>>>(
      t_in, ne_w1, ne_b1, ne_w2, ne_b2, router_w, nc_ws, tw, ti);
  mod_proj<<<dim3(B_, 8), dim3(1024), 0, stream>>>(
      nc_ws, ncsa_w, ncsa_b, moe_w, moe_b, ncsa_mod, moe_mod);

  // weight prep: 8 dense transposes + interleaved fc_in + fc_out transposes
  P8 dsrc;
  dsrc.p[0] = ca_wq; dsrc.p[1] = ca_wk; dsrc.p[2] = ca_wv; dsrc.p[3] = ca_wo;
  dsrc.p[4] = sa_wq; dsrc.p[5] = sa_wk; dsrc.p[6] = sa_wv; dsrc.p[7] = sa_wo;
  transpose_cvt8<<<dim3(16, 16, 8), 256, 0, stream>>>(dsrc, wT);
  transpose_cvt_ileave<<<dim3(128, 16, 8), 256, 0, stream>>>(fc_in_w, fciT);
  transpose_cvt<<<dim3(16, 64, 8), 256, 0, stream>>>(fc_out_w, fcoT, 2048, 512,
                                                     (long)2048 * 512, (long)2048 * 512);
  cvt_bf16<<<dim3(2048), 256, 0, stream>>>(scene, scene_bf);

  // scene cross-attention (K,V fused: N=1024, packed ckv)
  B3 bq1 = {{ca_bq, ca_bq, ca_bq}};
  B3 bkv = {{ca_bk, ca_bv, ca_bv}};
  B3 bo3 = {{ca_bo, ca_bo, ca_bo}};
  ln_mod_kernel<<<dim3(8192), 256, 0, stream>>>(x, sn_g, sn_b, nullptr, xin_bf);
  gemm_bf16<<<dim3(4, 64), 256, 0, stream>>>(xin_bf, wT + 0 * WSZ, bq1, nullptr, cq, 8192, 512, 512, 1);
  gemm_bf16<<<dim3(8, 32), 256, 0, stream>>>(scene_bf, wT + 1 * WSZ, bkv, nullptr, ckv, 4096, 1024, 512, 1);
  fattn_mfma<<<dim3(512), dim3(512), 0, stream>>>(cq, ckv, ckv + 512, attn_bf, NS_, 512, 1024);
  gemm_bf16<<<dim3(4, 64), 256, 0, stream>>>(attn_bf, wT + 3 * WSZ, bo3, x, x1, 8192, 512, 512, 0);

  // noise-conditioned self-attention (AdaLN); QKV fused: N=1536, packed qkv
  B3 bqkv = {{sa_bq, sa_bk, sa_bv}};
  B3 bso = {{sa_bo, sa_bo, sa_bo}};
  ln_mod_kernel<<<dim3(8192), 256, 0, stream>>>(x1, nullptr, nullptr, ncsa_mod, xin_bf);
  gemm_bf16<<<dim3(12, 64), 256, 0, stream>>>(xin_bf, wT + 4 * WSZ, bqkv, nullptr, qkv, 8192, 1536, 512, 1);
  fattn_mfma<<<dim3(512), dim3(512), 0, stream>>>(qkv, qkv + 512, qkv + 1024, attn_bf, L_, 1536, 1536);
  gemm_bf16<<<dim3(4, 64), 256, 0, stream>>>(attn_bf, wT + 7 * WSZ, bso, out, out, 8192, 512, 512, 0);

  // MoE (fcin: interleaved BK=32-swizzled GEMM, 5 blocks/CU; fcout: BK=64)
  ln_mod_kernel<<<dim3(8192), 256, 0, stream>>>(out, nullptr, nullptr, moe_mod, xin_bf);
  moe_fcin<<<dim3(2048), 256, 0, stream>>>(xin_bf, fciT, fc_in_b, tw, ti, hid, 0);
  moe_fcout<<<dim3(256), 256, 0, stream>>>(hid, fcoT, fc_out_b, out, tw, ti, out, 0, 1);
  moe_fcin<<<dim3(2048), 256, 0, stream>>>(xin_bf, fciT, fc_in_b, tw, ti, hid, 1);
  moe_fcout<<<dim3(256), 256, 0, stream>>>(hid, fcoT, fc_out_b, out, tw, ti, out, 1, 0);
}

// Round 10
// 677.904 us; speedup vs baseline: 1.0763x; 1.0763x over previous
//
#include <hip/hip_runtime.h>
#include <math.h>

typedef unsigned short ushort_t;
typedef __attribute__((ext_vector_type(8))) short short8;
typedef __attribute__((ext_vector_type(4))) float f32x4;

#define B_   8
#define L_   1024
#define NS_  512
#define D_   512
#define NH_  8
#define HE_  2048
#define EPS_ 1e-5f

#define MFMA16(a, b, c) __builtin_amdgcn_mfma_f32_16x16x32_bf16(a, b, c, 0, 0, 0)
#define GL2LDS(g, l) __builtin_amdgcn_global_load_lds( \
    (const __attribute__((address_space(1))) unsigned int*)(g), \
    (__attribute__((address_space(3))) unsigned int*)(l), 16, 0, 0)

__device__ __forceinline__ ushort_t f2bf(float f) {
  unsigned u = __float_as_uint(f);
  unsigned r = (u + 0x7fffu + ((u >> 16) & 1u)) >> 16;
  return (ushort_t)r;
}

// ---------------------------------------------------------------------------
// Stage a 128x32 bf16 tile (8 KB) with 2-bit XOR-swizzle (BK=32 variant):
// LDS dest linear; SOURCE chunk sc = (c&3) ^ ((row^(row>>2))&3).  Readers use
// chunk quad ^ ((r^(r>>2))&3) -> uniform 8 dwords/bank (bandwidth floor).
// ---------------------------------------------------------------------------
__device__ __forceinline__ void stage_tile32s(const ushort_t* __restrict__ g0,
                                              int ld, ushort_t* lds) {
  const int t = threadIdx.x;
  const int w = t >> 6, lane = t & 63;
#pragma unroll
  for (int j = 0; j < 2; ++j) {
    const int c = w * 64 + j * 256 + lane;
    const int row = c >> 2;
    const int sc = (c & 3) ^ ((row ^ (row >> 2)) & 3);
    GL2LDS(g0 + (size_t)row * ld + sc * 8, lds + (size_t)(w * 64 + j * 256) * 8);
  }
}

// ---------------------------------------------------------------------------
// Stage a 128x64 bf16 tile (16 KB) with XOR-swizzle (T2, rule #21):
// LDS dest stays linear; SOURCE chunk is inverse-swizzled so LDS chunk c
// holds global chunk (c&7)^(row&7).  Readers XOR chunk idx with (row&7).
// ---------------------------------------------------------------------------
__device__ __forceinline__ void stage_tile64(const ushort_t* __restrict__ g0,
                                             int ld, ushort_t* lds) {
  const int t = threadIdx.x;
  const int w = t >> 6, lane = t & 63;
#pragma unroll
  for (int j = 0; j < 4; ++j) {
    const int c = w * 64 + j * 256 + lane;
    const int row = c >> 3;
    const int sc = (c & 7) ^ (row & 7);
    GL2LDS(g0 + (size_t)row * ld + sc * 8, lds + (size_t)(w * 64 + j * 256) * 8);
  }
}

// ---------------------------------------------------------------------------
// Kernel 1a: noise embedding MLP + router top-2.  grid (B), 1024 thr.
// ---------------------------------------------------------------------------
__global__ __launch_bounds__(1024) void noise_embed(
    const float* __restrict__ t_in,
    const float* __restrict__ w1, const float* __restrict__ b1,
    const float* __restrict__ w2, const float* __restrict__ b2,
    const float* __restrict__ rw,
    float* __restrict__ nc_out,
    float* __restrict__ tw_out, int* __restrict__ ti_out)
{
  const int b = blockIdx.x;
  const int t = threadIdx.x;
  __shared__ float temb[512];
  __shared__ float h1[256];
  __shared__ float ncs[256];
  __shared__ float lg[8];
  const float tv = t_in[b];
  if (t < 512) {
    const int k = t & 255;
    float fr = __expf(-logf(10000.0f) * (float)k / 255.0f);
    float ang = tv * fr;
    temb[t] = (t < 256) ? cosf(ang) : sinf(ang);
  }
  __syncthreads();
  const int col = t >> 2, part = t & 3;
  {
    float s = 0.f;
    const float* wp = w1 + (size_t)(part * 128) * 256 + col;
    const float* tp = temb + part * 128;
#pragma unroll 32
    for (int i = 0; i < 128; ++i) s += tp[i] * wp[(size_t)i * 256];
    s += __shfl_xor(s, 1, 64);
    s += __shfl_xor(s, 2, 64);
    if (part == 0) {
      s += b1[col];
      h1[col] = s / (1.0f + __expf(-s));
    }
  }
  __syncthreads();
  {
    float s = 0.f;
    const float* wp = w2 + (size_t)(part * 64) * 256 + col;
    const float* hp = h1 + part * 64;
#pragma unroll 32
    for (int i = 0; i < 64; ++i) s += hp[i] * wp[(size_t)i * 256];
    s += __shfl_xor(s, 1, 64);
    s += __shfl_xor(s, 2, 64);
    if (part == 0) {
      s += b2[col];
      ncs[col] = s;
      nc_out[b * 256 + col] = s;
    }
  }
  __syncthreads();
  if (t < 64) {
    const int e = t >> 3, seg = t & 7;
    float s = 0.f;
#pragma unroll
    for (int i = 0; i < 32; ++i) s += ncs[seg * 32 + i] * rw[(seg * 32 + i) * 8 + e];
    s += __shfl_xor(s, 1, 64);
    s += __shfl_xor(s, 2, 64);
    s += __shfl_xor(s, 4, 64);
    if (seg == 0) lg[e] = s;
  }
  __syncthreads();
  if (t == 0) {
    float mx = lg[0];
    for (int e = 1; e < 8; ++e) mx = fmaxf(mx, lg[e]);
    float z = 0.f, p[8];
    for (int e = 0; e < 8; ++e) { p[e] = __expf(lg[e] - mx); z += p[e]; }
    for (int e = 0; e < 8; ++e) p[e] /= z;
    int i0 = 0;
    for (int e = 1; e < 8; ++e) if (p[e] > p[i0]) i0 = e;
    int i1 = (i0 == 0) ? 1 : 0;
    for (int e = 0; e < 8; ++e) if (e != i0 && p[e] > p[i1]) i1 = e;
    float s01 = fmaxf(p[i0] + p[i1], 1e-8f);
    tw_out[b * 2 + 0] = p[i0] / s01;
    tw_out[b * 2 + 1] = p[i1] / s01;
    ti_out[b * 2 + 0] = i0;
    ti_out[b * 2 + 1] = i1;
  }
}

// ---------------------------------------------------------------------------
// Kernel 1b: AdaLN modulation projections.  grid (B, 8), 1024 thr.
// ---------------------------------------------------------------------------
__global__ __launch_bounds__(1024) void mod_proj(
    const float* __restrict__ nc,
    const float* __restrict__ ncsa_w, const float* __restrict__ ncsa_b,
    const float* __restrict__ moe_w, const float* __restrict__ moe_b,
    float* __restrict__ ncsa_mod, float* __restrict__ moe_mod)
{
  const int b = blockIdx.x, cg = blockIdx.y;
  const int t = threadIdx.x;
  __shared__ float ncs[256];
  if (t < 256) ncs[t] = nc[b * 256 + t];
  __syncthreads();
  const int idx = t >> 2, part = t & 3;
  const int half = idx >> 7;
  const int col = cg * 128 + (idx & 127);
  const float* wsel = half ? moe_w : ncsa_w;
  float s = 0.f;
  const float* wp = wsel + (size_t)(part * 64) * 1024 + col;
  const float* np = ncs + part * 64;
#pragma unroll 32
  for (int i = 0; i < 64; ++i) s += np[i] * wp[(size_t)i * 1024];
  s += __shfl_xor(s, 1, 64);
  s += __shfl_xor(s, 2, 64);
  if (part == 0) {
    const float* bsel = half ? moe_b : ncsa_b;
    float* osel = half ? moe_mod : ncsa_mod;
    osel[b * 1024 + col] = s + bsel[col];
  }
}

// ---------------------------------------------------------------------------
// Kernel 2: LayerNorm + modulation -> bf16 output.
// ---------------------------------------------------------------------------
__global__ __launch_bounds__(256) void ln_mod_kernel(
    const float* __restrict__ X, const float* __restrict__ gvec,
    const float* __restrict__ bvec, const float* __restrict__ mod,
    ushort_t* __restrict__ Y)
{
  const int row = blockIdx.x;
  const int b = row >> 10;
  const int t = threadIdx.x;
  const float* xr = X + (size_t)row * 512;
  float2 v = *(const float2*)(xr + t * 2);
  float s = v.x + v.y;
  float q = v.x * v.x + v.y * v.y;
#pragma unroll
  for (int off = 32; off > 0; off >>= 1) {
    s += __shfl_down(s, off, 64);
    q += __shfl_down(q, off, 64);
  }
  __shared__ float ws_[4], wq_[4], smu[1], sinv[1];
  if ((t & 63) == 0) { ws_[t >> 6] = s; wq_[t >> 6] = q; }
  __syncthreads();
  if (t == 0) {
    float S = ws_[0] + ws_[1] + ws_[2] + ws_[3];
    float Q = wq_[0] + wq_[1] + wq_[2] + wq_[3];
    float mu = S * (1.0f / 512.0f);
    float var = Q * (1.0f / 512.0f) - mu * mu;
    smu[0] = mu;
    sinv[0] = rsqrtf(var + EPS_);
  }
  __syncthreads();
  const float mu = smu[0], inv = sinv[0];
  const int d0 = t * 2;
  float scx, scy, shx, shy;
  if (mod) {
    const float* mrow = mod + (size_t)b * 1024;
    scx = 1.0f + mrow[512 + d0]; scy = 1.0f + mrow[512 + d0 + 1];
    shx = mrow[d0];              shy = mrow[d0 + 1];
  } else {
    scx = gvec[d0]; scy = gvec[d0 + 1];
    shx = bvec[d0]; shy = bvec[d0 + 1];
  }
  float ox = (v.x - mu) * inv * scx + shx;
  float oy = (v.y - mu) * inv * scy + shy;
  unsigned pk = (unsigned)f2bf(ox) | ((unsigned)f2bf(oy) << 16);
  *(unsigned*)(Y + (size_t)row * 512 + d0) = pk;
}

// ---------------------------------------------------------------------------
// Kernel 3a: tiled transpose + fp32->bf16:  in[z][R][C] -> out[z][C][R]
// ---------------------------------------------------------------------------
__global__ __launch_bounds__(256) void transpose_cvt(
    const float* __restrict__ in, ushort_t* __restrict__ out,
    int R, int C, long ibs, long obs)
{
  __shared__ float tile[32][33];
  const float* src = in + (size_t)blockIdx.z * ibs;
  ushort_t* dst = out + (size_t)blockIdx.z * obs;
  const int c0 = blockIdx.x * 32, r0 = blockIdx.y * 32;
  const int tx = threadIdx.x & 31, ty = threadIdx.x >> 5;
  for (int rr = ty; rr < 32; rr += 8)
    tile[rr][tx] = src[(size_t)(r0 + rr) * C + c0 + tx];
  __syncthreads();
  for (int rr = ty; rr < 32; rr += 8)
    dst[(size_t)(c0 + rr) * R + r0 + tx] = f2bf(tile[tx][rr]);
}

// Kernel 3a'': interleaved transpose for fc_in_w: in[e][512][4096] ->
// out[e][4096][512] where out row c holds source col (c>>1) + (c&1)*2048.
// Permutation applied on the WRITE side: block reads a contiguous 32x32
// source tile (full 128B-coalesced reads); source col sc maps to dst row
// ((sc&2047)<<1) | (sc>>11).
__global__ __launch_bounds__(256) void transpose_cvt_ileave(
    const float* __restrict__ in, ushort_t* __restrict__ out)
{
  __shared__ float tile[32][33];
  const int e = blockIdx.z;
  const int sc0 = blockIdx.x * 32, d0 = blockIdx.y * 32;
  const int tx = threadIdx.x & 31, ty = threadIdx.x >> 5;
  const float* src = in + (size_t)e * 512 * 4096;
  ushort_t* dst = out + (size_t)e * 4096 * 512;
  const int half = sc0 >> 11;        // whole block is one half (32 | 2048)
  for (int rr = ty; rr < 32; rr += 8)
    tile[rr][tx] = src[(size_t)(d0 + rr) * 4096 + sc0 + tx];
  __syncthreads();
  for (int rr = ty; rr < 32; rr += 8) {
    const int drow = (((sc0 + rr) & 2047) << 1) | half;
    dst[(size_t)drow * 512 + d0 + tx] = f2bf(tile[tx][rr]);
  }
}

// Kernel 3a': 8 dense 512x512 transposes in one dispatch (z selects source).
struct P8 { const float* p[8]; };
__global__ __launch_bounds__(256) void transpose_cvt8(
    P8 srcs, ushort_t* __restrict__ out)
{
  __shared__ float tile[32][33];
  const float* src = srcs.p[blockIdx.z];
  ushort_t* dst = out + (size_t)blockIdx.z * 512 * 512;
  const int c0 = blockIdx.x * 32, r0 = blockIdx.y * 32;
  const int tx = threadIdx.x & 31, ty = threadIdx.x >> 5;
  for (int rr = ty; rr < 32; rr += 8)
    tile[rr][tx] = src[(size_t)(r0 + rr) * 512 + c0 + tx];
  __syncthreads();
  for (int rr = ty; rr < 32; rr += 8)
    dst[(size_t)(c0 + rr) * 512 + r0 + tx] = f2bf(tile[tx][rr]);
}

// Kernel 3b: plain fp32->bf16 cast (4 elems/thread)
__global__ __launch_bounds__(256) void cvt_bf16(
    const float* __restrict__ in, ushort_t* __restrict__ out)
{
  const int i = (blockIdx.x * 256 + threadIdx.x) * 4;
  float4 v = *(const float4*)(in + i);
  uint2 pk;
  pk.x = (unsigned)f2bf(v.x) | ((unsigned)f2bf(v.y) << 16);
  pk.y = (unsigned)f2bf(v.z) | ((unsigned)f2bf(v.w) << 16);
  *(uint2*)(out + i) = pk;
}

// ---------------------------------------------------------------------------
// Kernel 4: bf16 MFMA GEMM.  C[M,N] = A[M,K](bf16) @ Bt[N,K]^T + bias (+resid)
// 128x128 tile, BK=64 swizzled LDS (T2), 4 waves, double-buffered (64 KB).
// ---------------------------------------------------------------------------
struct B3 { const float* p[3]; };
__global__ __launch_bounds__(256) void gemm_bf16(
    const ushort_t* __restrict__ A, const ushort_t* __restrict__ Bt,
    B3 bias, const float* __restrict__ resid,
    void* __restrict__ Cout, int M, int N, int K, int bf16_out)
{
  __shared__ ushort_t As[2][8192];
  __shared__ ushort_t Bs[2][8192];
  const int t = threadIdx.x;
  const int w = t >> 6, lane = t & 63;
  const int quad = lane >> 4, r = lane & 15;
  const int sw = r & 7;
  const int wm = w >> 1, wn = w & 1;
  const int gx = gridDim.x;
  const int T = gx * gridDim.y;
  const int lid = blockIdx.x + gx * blockIdx.y;
  const int nl = (lid & 7) * (T >> 3) + (lid >> 3);
  const int bm = (nl / gx) * 128, bn = (nl % gx) * 128;
  f32x4 acc[4][4];
#pragma unroll
  for (int i = 0; i < 4; ++i)
#pragma unroll
    for (int j = 0; j < 4; ++j) acc[i][j] = (f32x4){0.f, 0.f, 0.f, 0.f};
  const ushort_t* Ab = A + (size_t)bm * K;
  const ushort_t* Bb = Bt + (size_t)bn * K;
  const int NIT = K >> 6;
  stage_tile64(Ab, K, As[0]);
  stage_tile64(Bb, K, Bs[0]);
  __syncthreads();
  for (int it = 0; it < NIT; ++it) {
    const int cur = it & 1;
    if (it + 1 < NIT) {
      stage_tile64(Ab + (it + 1) * 64, K, As[cur ^ 1]);
      stage_tile64(Bb + (it + 1) * 64, K, Bs[cur ^ 1]);
    }
#pragma unroll
    for (int ki = 0; ki < 2; ++ki) {
      const int ch = (((ki << 2) | quad) ^ sw) * 8;
      short8 af[4], bfg[4];
#pragma unroll
      for (int i = 0; i < 4; ++i)
        af[i] = *(const short8*)&As[cur][(wm * 64 + i * 16 + r) * 64 + ch];
#pragma unroll
      for (int j = 0; j < 4; ++j)
        bfg[j] = *(const short8*)&Bs[cur][(wn * 64 + j * 16 + r) * 64 + ch];
#pragma unroll
      for (int i = 0; i < 4; ++i)
#pragma unroll
        for (int j = 0; j < 4; ++j)
          acc[i][j] = MFMA16(af[i], bfg[j], acc[i][j]);
    }
    __syncthreads();
  }
  if (bf16_out) {
    ushort_t* Cb = (ushort_t*)Cout;
#pragma unroll
    for (int j = 0; j < 4; ++j) {
      const int col = bn + wn * 64 + j * 16 + r;
      const float bia = bias.p[col >> 9][col & 511];
#pragma unroll
      for (int i = 0; i < 4; ++i)
#pragma unroll
        for (int reg = 0; reg < 4; ++reg) {
          const int row = bm + wm * 64 + i * 16 + quad * 4 + reg;
          Cb[(size_t)row * N + col] = f2bf(acc[i][j][reg] + bia);
        }
    }
  } else {
    float* Cf = (float*)Cout;
#pragma unroll
    for (int j = 0; j < 4; ++j) {
      const int col = bn + wn * 64 + j * 16 + r;
      const float bia = bias.p[col >> 9][col & 511];
#pragma unroll
      for (int i = 0; i < 4; ++i)
#pragma unroll
        for (int reg = 0; reg < 4; ++reg) {
          const int row = bm + wm * 64 + i * 16 + quad * 4 + reg;
          float v = acc[i][j][reg] + bia;
          if (resid) v += resid[(size_t)row * N + col];
          Cf[(size_t)row * N + col] = v;
        }
    }
  }
}

// ---------------------------------------------------------------------------
// Kernel 5: MFMA flash attention, bf16 Q/K/V in, bf16 out.
// Flat grid of 512 blocks x 512 thr (8 waves); each block = 128 queries,
// wave w owns queries w*16..w*16+15.  XCD grouping: bid&7 -> XCD.
// ---------------------------------------------------------------------------
__global__ __launch_bounds__(512, 4) void fattn_mfma(
    const ushort_t* __restrict__ Q, const ushort_t* __restrict__ Kmat,
    const ushort_t* __restrict__ V, ushort_t* __restrict__ O, int Lk,
    int ldq, int ldkv)
{
  __shared__ __align__(16) ushort_t Ks[64][72];      // [key][d]
  __shared__ __align__(16) ushort_t Vt[64][72];      // [d][key]
  __shared__ __align__(16) ushort_t Pt[8][16][72];   // per-wave [q_local][key]
  const int t = threadIdx.x;
  const int w = t >> 6, lane = t & 63;
  const int quad = lane >> 4, r = lane & 15;
  const int bid = blockIdx.x;
  const int xcd = bid & 7, jj = bid >> 3;
  const int qi = jj & 7;                 // q-tile 0..7
  const int g = xcd + 8 * (jj >> 3);     // (b,h) group 0..63
  const int h = g & 7, b = g >> 3;
  const int q0 = qi * 128;
  const size_t hoff = (size_t)h * 64;
  const ushort_t* Qb = Q + ((size_t)b * 1024 + q0) * ldq + hoff;
  const ushort_t* Kb = Kmat + (size_t)b * Lk * ldkv + hoff;
  const ushort_t* Vb = V + (size_t)b * Lk * ldkv + hoff;

  short8 qb[2];
#pragma unroll
  for (int ki = 0; ki < 2; ++ki)
    qb[ki] = *(const short8*)(Qb + (size_t)(w * 16 + r) * ldq +
                              ki * 32 + quad * 8);

  f32x4 oacc[4];
#pragma unroll
  for (int rt = 0; rt < 4; ++rt) oacc[rt] = (f32x4){0.f, 0.f, 0.f, 0.f};
  float m_ = -1e30f;
  float l_ = 0.f;

  uint4 kr, vr, kn, vn;
  const int dof = w * 8;                 // this wave's d-slice of K/V rows
  auto ldkvf = [&](int k0, uint4& kp, uint4& vp) {
    kp = *(const uint4*)(Kb + (size_t)(k0 + lane) * ldkv + dof);
    vp = *(const uint4*)(Vb + (size_t)(k0 + lane) * ldkv + dof);
  };
  auto stkv = [&](const uint4& kp, const uint4& vp) {
    *(uint4*)&Ks[lane][dof] = kp;
    const ushort_t* vv = (const ushort_t*)&vp;
#pragma unroll
    for (int i = 0; i < 8; ++i) Vt[dof + i][lane] = vv[i];  // transpose
  };

  ldkvf(0, kr, vr);
  const int nch = Lk >> 6;
  for (int c = 0; c < nch; ++c) {
    stkv(kr, vr);
    __syncthreads();
    if (c + 1 < nch) ldkvf((c + 1) << 6, kn, vn);

    // ---- S^T = K · Q^T ----
    f32x4 sacc[4];
#pragma unroll
    for (int rt = 0; rt < 4; ++rt) sacc[rt] = (f32x4){0.f, 0.f, 0.f, 0.f};
    __builtin_amdgcn_s_setprio(1);
#pragma unroll
    for (int ki = 0; ki < 2; ++ki) {
      short8 kf[4];
#pragma unroll
      for (int rt = 0; rt < 4; ++rt)
        kf[rt] = *(const short8*)&Ks[rt * 16 + r][ki * 32 + quad * 8];
#pragma unroll
      for (int rt = 0; rt < 4; ++rt)
        sacc[rt] = MFMA16(kf[rt], qb[ki], sacc[rt]);
    }
    __builtin_amdgcn_s_setprio(0);

    // ---- online softmax with defer-max (T13) ----
    {
      float vmax = sacc[0][0];
#pragma unroll
      for (int rt = 0; rt < 4; ++rt)
#pragma unroll
        for (int reg = 0; reg < 4; ++reg) vmax = fmaxf(vmax, sacc[rt][reg]);
      vmax = fmaxf(vmax, __shfl_xor(vmax, 16, 64));
      vmax = fmaxf(vmax, __shfl_xor(vmax, 32, 64));
      const float pm = vmax * 0.125f;
      if (__any(pm > m_ + 8.f)) {
        const float mnew = fmaxf(m_, pm);
        const float corr = __expf(m_ - mnew);
        m_ = mnew;
        l_ *= corr;
#pragma unroll
        for (int rt = 0; rt < 4; ++rt)
#pragma unroll
          for (int reg = 0; reg < 4; ++reg) oacc[rt][reg] *= corr;
      }
      const float mcur = m_;
      float ps = 0.f;
#pragma unroll
      for (int rt = 0; rt < 4; ++rt) {
        float p0 = __expf(fmaf(sacc[rt][0], 0.125f, -mcur));
        float p1 = __expf(fmaf(sacc[rt][1], 0.125f, -mcur));
        float p2 = __expf(fmaf(sacc[rt][2], 0.125f, -mcur));
        float p3 = __expf(fmaf(sacc[rt][3], 0.125f, -mcur));
        ps += (p0 + p1) + (p2 + p3);
        uint2 pk;
        pk.x = (unsigned)f2bf(p0) | ((unsigned)f2bf(p1) << 16);
        pk.y = (unsigned)f2bf(p2) | ((unsigned)f2bf(p3) << 16);
        *(uint2*)&Pt[w][r][rt * 16 + quad * 4] = pk;
      }
      ps += __shfl_xor(ps, 16, 64);
      ps += __shfl_xor(ps, 32, 64);
      l_ += ps;
    }

    // ---- O^T += V^T · P^T ----
    __builtin_amdgcn_s_setprio(1);
#pragma unroll
    for (int ki = 0; ki < 2; ++ki) {
      short8 vf[4], pf;
#pragma unroll
      for (int rt = 0; rt < 4; ++rt)
        vf[rt] = *(const short8*)&Vt[rt * 16 + r][ki * 32 + quad * 8];
      pf = *(const short8*)&Pt[w][r][ki * 32 + quad * 8];
#pragma unroll
      for (int rt = 0; rt < 4; ++rt)
        oacc[rt] = MFMA16(vf[rt], pf, oacc[rt]);
    }
    __builtin_amdgcn_s_setprio(0);
    __syncthreads();
    kr = kn; vr = vn;
  }

  // ---- epilogue ----
  {
    const float inv = 1.0f / l_;
    const int qg = q0 + w * 16 + r;
    ushort_t* op = O + ((size_t)b * 1024 + qg) * 512 + hoff;
#pragma unroll
    for (int rt = 0; rt < 4; ++rt) {
      uint2 pk;
      pk.x = (unsigned)f2bf(oacc[rt][0] * inv) |
             ((unsigned)f2bf(oacc[rt][1] * inv) << 16);
      pk.y = (unsigned)f2bf(oacc[rt][2] * inv) |
             ((unsigned)f2bf(oacc[rt][3] * inv) << 16);
      *(uint2*)(op + rt * 16 + quad * 4) = pk;
    }
  }
}

// ---------------------------------------------------------------------------
// Kernel 6: MoE fc_in for ONE slot, interleaved-weight GEMM.  flat 2048 blks.
// WiT_int[e][4096][512]: row c = source col (c>>1)+(c&1)*2048; SwiGLU fuses
// via shfl_xor(.,1).  BK=32 + 2-bit swizzle, 32 KB LDS.
// __launch_bounds__(256, 4): VGPR cap 128 (acc alone is 64; round-9's (256,5)
// capped VGPR at 48 -> accumulator spilled to scratch, WRITE 120 MB).
// 4 blocks/CU (VGPR-bound; LDS would allow 5) = 2x round-8 residency.
// XCD remap: b == xcd; r0 inner (8 consecutive blocks share a weight panel).
// ---------------------------------------------------------------------------
__global__ __launch_bounds__(256, 4) void moe_fcin(
    const ushort_t* __restrict__ Xm, const ushort_t* __restrict__ WiT,
    const float* __restrict__ Bi, const float* __restrict__ tw,
    const int* __restrict__ ti, ushort_t* __restrict__ Hid, int ks)
{
  __shared__ ushort_t As[2][4096];
  __shared__ ushort_t Bs[2][4096];
  const int t = threadIdx.x;
  const int w = t >> 6, lane = t & 63;
  const int quad = lane >> 4, r = lane & 15;
  const int sw = (r ^ (r >> 2)) & 3;
  const int wm = w >> 1, wn = w & 1;
  const int lid = blockIdx.x;
  const int nl = (lid & 7) * 256 + (lid >> 3);
  const int r0 = (nl & 7) * 128;           // inner: A row-band
  const int n0 = ((nl >> 3) & 31) * 128;   // middle: weight panel
  const int b = nl >> 8;
  const int e = ti[b * 2 + ks];
  const float wq = tw[b * 2 + ks];
  f32x4 acc[4][4];
#pragma unroll
  for (int i = 0; i < 4; ++i)
#pragma unroll
    for (int j = 0; j < 4; ++j) acc[i][j] = (f32x4){0.f, 0.f, 0.f, 0.f};
  const ushort_t* Ab = Xm + ((size_t)b * 1024 + r0) * 512;
  const ushort_t* Bb = WiT + (size_t)e * 4096 * 512 + (size_t)n0 * 512;
  stage_tile32s(Ab, 512, As[0]);
  stage_tile32s(Bb, 512, Bs[0]);
  __syncthreads();
  for (int it = 0; it < 16; ++it) {
    const int cur = it & 1;
    if (it + 1 < 16) {
      stage_tile32s(Ab + (it + 1) * 32, 512, As[cur ^ 1]);
      stage_tile32s(Bb + (it + 1) * 32, 512, Bs[cur ^ 1]);
    }
    const int ch = (quad ^ sw) * 8;
    short8 af[4], bfg[4];
#pragma unroll
    for (int i = 0; i < 4; ++i)
      af[i] = *(const short8*)&As[cur][(wm * 64 + i * 16 + r) * 32 + ch];
#pragma unroll
    for (int j = 0; j < 4; ++j)
      bfg[j] = *(const short8*)&Bs[cur][(wn * 64 + j * 16 + r) * 32 + ch];
#pragma unroll
    for (int i = 0; i < 4; ++i)
#pragma unroll
      for (int j = 0; j < 4; ++j)
        acc[i][j] = MFMA16(af[i], bfg[j], acc[i][j]);
    __syncthreads();
  }
  // epilogue: col = interleaved index; oc = col>>1; even lane = val, odd = gate
  ushort_t* Hb = Hid + (size_t)b * 1024 * 2048;
#pragma unroll
  for (int j = 0; j < 4; ++j) {
    const int col = n0 + wn * 64 + j * 16 + r;
    const int oc = col >> 1;
    const float bia = Bi[(size_t)e * 4096 + oc + (col & 1) * 2048];
#pragma unroll
    for (int i = 0; i < 4; ++i)
#pragma unroll
      for (int reg = 0; reg < 4; ++reg) {
        const float mine = acc[i][j][reg] + bia;
        const float part = __shfl_xor(mine, 1, 64);
        if ((r & 1) == 0) {
          const float gg = part;                       // odd lane held gate
          const float hv = mine * (gg / (1.0f + __expf(-gg))) * wq;
          const int lrow = r0 + wm * 64 + i * 16 + quad * 4 + reg;
          Hb[(size_t)lrow * 2048 + oc] = f2bf(hv);
        }
      }
  }
}

// ---------------------------------------------------------------------------
// Kernel 7: MoE fc_out for ONE slot.  flat grid 256, 256 thr.  BK=64 + T2.
// first=1: Out = X2 + acc + (tw0*bo_e0 + tw1*bo_e1);  first=0: Out += acc
// ---------------------------------------------------------------------------
__global__ __launch_bounds__(256) void moe_fcout(
    const ushort_t* __restrict__ Hid, const ushort_t* __restrict__ WoT,
    const float* __restrict__ Bo, const float* __restrict__ X2,
    const float* __restrict__ tw, const int* __restrict__ ti,
    float* __restrict__ Out, int ks, int first)
{
  __shared__ ushort_t As[2][8192];
  __shared__ ushort_t Bs[2][8192];
  const int t = threadIdx.x;
  const int w = t >> 6, lane = t & 63;
  const int quad = lane >> 4, r = lane & 15;
  const int sw = r & 7;
  const int wm = w >> 1, wn = w & 1;
  const int lid = blockIdx.x;
  const int nl = (lid & 7) * 32 + (lid >> 3);
  const int n0 = (nl & 3) * 128;
  const int r0 = ((nl >> 2) & 7) * 128;
  const int b = nl >> 5;
  const int e = ti[b * 2 + ks];
  f32x4 acc[4][4];
#pragma unroll
  for (int i = 0; i < 4; ++i)
#pragma unroll
    for (int j = 0; j < 4; ++j) acc[i][j] = (f32x4){0.f, 0.f, 0.f, 0.f};
  const ushort_t* Ab = Hid + ((size_t)b * 1024 + r0) * 2048;
  const ushort_t* Bb = WoT + (size_t)e * 512 * 2048 + (size_t)n0 * 2048;
  stage_tile64(Ab, 2048, As[0]);
  stage_tile64(Bb, 2048, Bs[0]);
  __syncthreads();
  for (int it = 0; it < 32; ++it) {
    const int cur = it & 1;
    if (it + 1 < 32) {
      stage_tile64(Ab + (it + 1) * 64, 2048, As[cur ^ 1]);
      stage_tile64(Bb + (it + 1) * 64, 2048, Bs[cur ^ 1]);
    }
#pragma unroll
    for (int ki = 0; ki < 2; ++ki) {
      const int ch = (((ki << 2) | quad) ^ sw) * 8;
      short8 af[4], bfg[4];
#pragma unroll
      for (int i = 0; i < 4; ++i)
        af[i] = *(const short8*)&As[cur][(wm * 64 + i * 16 + r) * 64 + ch];
#pragma unroll
      for (int j = 0; j < 4; ++j)
        bfg[j] = *(const short8*)&Bs[cur][(wn * 64 + j * 16 + r) * 64 + ch];
#pragma unroll
      for (int i = 0; i < 4; ++i)
#pragma unroll
        for (int j = 0; j < 4; ++j)
          acc[i][j] = MFMA16(af[i], bfg[j], acc[i][j]);
    }
    __syncthreads();
  }
  const int e0 = ti[b * 2], e1 = ti[b * 2 + 1];
  const float tw0 = tw[b * 2], tw1 = tw[b * 2 + 1];
#pragma unroll
  for (int j = 0; j < 4; ++j) {
    const int col = n0 + wn * 64 + j * 16 + r;
    const float badd = first ? (tw0 * Bo[(size_t)e0 * 512 + col] +
                                tw1 * Bo[(size_t)e1 * 512 + col]) : 0.f;
#pragma unroll
    for (int i = 0; i < 4; ++i)
#pragma unroll
      for (int reg = 0; reg < 4; ++reg) {
        const size_t row = (size_t)b * 1024 + r0 + wm * 64 + i * 16 + quad * 4 + reg;
        const size_t idx = row * 512 + col;
        const float base = first ? X2[idx] : Out[idx];
        Out[idx] = base + acc[i][j][reg] + badd;
      }
  }
}

// ---------------------------------------------------------------------------
// Launch.  Workspace: 93 MiB total.
// ---------------------------------------------------------------------------
extern "C" void kernel_launch(void* const* d_in, const int* in_sizes, int n_in,
                              void* d_out, int out_size, void* d_ws, size_t ws_size,
                              hipStream_t stream) {
  const float* x        = (const float*)d_in[0];
  const float* scene    = (const float*)d_in[1];
  const float* t_in     = (const float*)d_in[2];
  const float* sn_g     = (const float*)d_in[3];
  const float* sn_b     = (const float*)d_in[4];
  const float* ca_wq    = (const float*)d_in[5];
  const float* ca_bq    = (const float*)d_in[6];
  const float* ca_wk    = (const float*)d_in[7];
  const float* ca_bk    = (const float*)d_in[8];
  const float* ca_wv    = (const float*)d_in[9];
  const float* ca_bv    = (const float*)d_in[10];
  const float* ca_wo    = (const float*)d_in[11];
  const float* ca_bo    = (const float*)d_in[12];
  const float* sa_wq    = (const float*)d_in[13];
  const float* sa_bq    = (const float*)d_in[14];
  const float* sa_wk    = (const float*)d_in[15];
  const float* sa_bk    = (const float*)d_in[16];
  const float* sa_wv    = (const float*)d_in[17];
  const float* sa_bv    = (const float*)d_in[18];
  const float* sa_wo    = (const float*)d_in[19];
  const float* sa_bo    = (const float*)d_in[20];
  const float* ne_w1    = (const float*)d_in[21];
  const float* ne_b1    = (const float*)d_in[22];
  const float* ne_w2    = (const float*)d_in[23];
  const float* ne_b2    = (const float*)d_in[24];
  const float* ncsa_w   = (const float*)d_in[25];
  const float* ncsa_b   = (const float*)d_in[26];
  const float* moe_w    = (const float*)d_in[27];
  const float* moe_b    = (const float*)d_in[28];
  const float* router_w = (const float*)d_in[29];
  const float* fc_in_w  = (const float*)d_in[30];
  const float* fc_in_b  = (const float*)d_in[31];
  const float* fc_out_w = (const float*)d_in[32];
  const float* fc_out_b = (const float*)d_in[33];
  float* out = (float*)d_out;

  // ---- workspace layout (MiB offsets; 93 MiB total) ----
  char* W = (char*)d_ws;
  const size_t MB = 1u << 20;
  float* ncsa_mod = (float*)W;
  float* moe_mod  = ncsa_mod + 8192;
  float* tw       = moe_mod + 8192;
  int*   ti       = (int*)(tw + 16);
  float* nc_ws    = (float*)(ti + 16);            // [8][256]
  ushort_t* wT      = (ushort_t*)(W + 1 * MB);
  ushort_t* fciT    = (ushort_t*)(W + 5 * MB);
  ushort_t* fcoT    = (ushort_t*)(W + 37 * MB);
  ushort_t* xin_bf  = (ushort_t*)(W + 53 * MB);
  ushort_t* attn_bf = xin_bf;
  ushort_t* scene_bf= (ushort_t*)(W + 61 * MB);
  ushort_t* cq  = (ushort_t*)(W + 65 * MB);
  ushort_t* ckv = (ushort_t*)(W + 73 * MB);
  ushort_t* qkv = (ushort_t*)(W + 65 * MB);
  ushort_t* hid = (ushort_t*)(W + 61 * MB);
  float* x1 = out;

  const int WSZ = 512 * 512;

  // noise path: embed+router (8 blocks x 1024 thr), then mods (64 x 1024 thr)
  noise_embed<<<dim3(B_), dim3(1024), 0, stream>>>(
      t_in, ne_w1, ne_b1, ne_w2, ne_b2, router_w, nc_ws, tw, ti);
  mod_proj<<<dim3(B_, 8), dim3(1024), 0, stream>>>(
      nc_ws, ncsa_w, ncsa_b, moe_w, moe_b, ncsa_mod, moe_mod);

  // weight prep: 8 dense transposes + interleaved fc_in + fc_out transposes
  P8 dsrc;
  dsrc.p[0] = ca_wq; dsrc.p[1] = ca_wk; dsrc.p[2] = ca_wv; dsrc.p[3] = ca_wo;
  dsrc.p[4] = sa_wq; dsrc.p[5] = sa_wk; dsrc.p[6] = sa_wv; dsrc.p[7] = sa_wo;
  transpose_cvt8<<<dim3(16, 16, 8), 256, 0, stream>>>(dsrc, wT);
  transpose_cvt_ileave<<<dim3(128, 16, 8), 256, 0, stream>>>(fc_in_w, fciT);
  transpose_cvt<<<dim3(16, 64, 8), 256, 0, stream>>>(fc_out_w, fcoT, 2048, 512,
                                                     (long)2048 * 512, (long)2048 * 512);
  cvt_bf16<<<dim3(2048), 256, 0, stream>>>(scene, scene_bf);

  // scene cross-attention (K,V fused: N=1024, packed ckv)
  B3 bq1 = {{ca_bq, ca_bq, ca_bq}};
  B3 bkv = {{ca_bk, ca_bv, ca_bv}};
  B3 bo3 = {{ca_bo, ca_bo, ca_bo}};
  ln_mod_kernel<<<dim3(8192), 256, 0, stream>>>(x, sn_g, sn_b, nullptr, xin_bf);
  gemm_bf16<<<dim3(4, 64), 256, 0, stream>>>(xin_bf, wT + 0 * WSZ, bq1, nullptr, cq, 8192, 512, 512, 1);
  gemm_bf16<<<dim3(8, 32), 256, 0, stream>>>(scene_bf, wT + 1 * WSZ, bkv, nullptr, ckv, 4096, 1024, 512, 1);
  fattn_mfma<<<dim3(512), dim3(512), 0, stream>>>(cq, ckv, ckv + 512, attn_bf, NS_, 512, 1024);
  gemm_bf16<<<dim3(4, 64), 256, 0, stream>>>(attn_bf, wT + 3 * WSZ, bo3, x, x1, 8192, 512, 512, 0);

  // noise-conditioned self-attention (AdaLN); QKV fused: N=1536, packed qkv
  B3 bqkv = {{sa_bq, sa_bk, sa_bv}};
  B3 bso = {{sa_bo, sa_bo, sa_bo}};
  ln_mod_kernel<<<dim3(8192), 256, 0, stream>>>(x1, nullptr, nullptr, ncsa_mod, xin_bf);
  gemm_bf16<<<dim3(12, 64), 256, 0, stream>>>(xin_bf, wT + 4 * WSZ, bqkv, nullptr, qkv, 8192, 1536, 512, 1);
  fattn_mfma<<<dim3(512), dim3(512), 0, stream>>>(qkv, qkv + 512, qkv + 1024, attn_bf, L_, 1536, 1536);
  gemm_bf16<<<dim3(4, 64), 256, 0, stream>>>(attn_bf, wT + 7 * WSZ, bso, out, out, 8192, 512, 512, 0);

  // MoE (fcin: interleaved BK=32-swizzled GEMM, 4 blocks/CU; fcout: BK=64)
  ln_mod_kernel<<<dim3(8192), 256, 0, stream>>>(out, nullptr, nullptr, moe_mod, xin_bf);
  moe_fcin<<<dim3(2048), 256, 0, stream>>>(xin_bf, fciT, fc_in_b, tw, ti, hid, 0);
  moe_fcout<<<dim3(256), 256, 0, stream>>>(hid, fcoT, fc_out_b, out, tw, ti, out, 0, 1);
  moe_fcin<<<dim3(2048), 256, 0, stream>>>(xin_bf, fciT, fc_in_b, tw, ti, hid, 1);
  moe_fcout<<<dim3(256), 256, 0, stream>>>(hid, fcoT, fc_out_b, out, tw, ti, out, 1, 0);
}